// Round 2
// baseline (1447.246 us; speedup 1.0000x reference)
//
#include <hip/hip_runtime.h>
#include <math.h>
#include <stdint.h>

#define Bz 64
#define Tz 32
#define Ez 64
#define Hz 256
#define Vz 32000
#define KTOT 320   // Ez + Hz

typedef unsigned long long u64;
typedef unsigned int u32;

__device__ __forceinline__ u32 map_f32(float f) {
  u32 u = __float_as_uint(f);
  return (u & 0x80000000u) ? ~u : (u | 0x80000000u);
}

// ---------------- weight repack: P2[j][g][k] contiguous k-runs; zero key bufs -----------
__global__ void k_prep(const float* __restrict__ Wi, const float* __restrict__ Ui,
                       const float* __restrict__ Wf, const float* __restrict__ Uf,
                       const float* __restrict__ Wog, const float* __restrict__ Uog,
                       const float* __restrict__ Wc, const float* __restrict__ Uc,
                       float* __restrict__ P2, u64* __restrict__ key) {
  int j = blockIdx.x;        // 0..255
  int k = threadIdx.x;       // 0..319
  float g0, g1, g2, g3;
  if (k < Ez) {
    g0 = Wi[k*Hz + j]; g1 = Wf[k*Hz + j]; g2 = Wog[k*Hz + j]; g3 = Wc[k*Hz + j];
  } else {
    int kk = k - Ez;
    g0 = Ui[kk*Hz + j]; g1 = Uf[kk*Hz + j]; g2 = Uog[kk*Hz + j]; g3 = Uc[kk*Hz + j];
  }
  P2[(size_t)(j*4 + 0)*KTOT + k] = g0;
  P2[(size_t)(j*4 + 1)*KTOT + k] = g1;
  P2[(size_t)(j*4 + 2)*KTOT + k] = g2;
  P2[(size_t)(j*4 + 3)*KTOT + k] = g3;
  if (j == 0 && k < 2*Bz) key[k] = 0ull;   // both parity buffers
}

// ---------------- per-step LSTM cell: 256 blocks (one j each) x 256 thr (64b x 4 gates) --
__global__ __launch_bounds__(256) void k_gates(
    int t, const int* __restrict__ gnp,
    const int* __restrict__ input_x, const int* __restrict__ start_tok,
    const float* __restrict__ emb, const float* __restrict__ P2,
    const float* __restrict__ bi_, const float* __restrict__ bf_,
    const float* __restrict__ bog_, const float* __restrict__ bc_,
    const float* __restrict__ h_in, float* __restrict__ h_out,
    float* __restrict__ c_g, float* __restrict__ hT,
    const u64* __restrict__ key_prev, u64* __restrict__ key_cur,
    int* __restrict__ out) {
  __shared__ int tok_s[Bz];
  int tid = threadIdx.x;
  int j = blockIdx.x;          // 0..255
  int b = tid >> 2, q = tid & 3;
  int gn = *gnp;

  // ---- token pick for step t (cheap: one key read) ----
  if (q == 0) {
    int tk;
    if (t == 0) tk = start_tok[b];
    else if (t - 1 < gn) tk = input_x[b*Tz + (t - 1)];
    else tk = (int)(~(u32)(key_prev[b] & 0xFFFFFFFFull));
    tok_s[b] = tk;
    if (j == 0 && t > 0) out[b*Tz + (t - 1)] = tk;
  }
  if (j == 0 && q == 1) key_cur[b] = 0ull;   // reset for this step's k_logits
  __syncthreads();

  // ---- one gate dot per thread: gate q of (b, j), K = 64 emb + 256 h ----
  const float* wrow = P2 + (size_t)(j*4 + q)*KTOT;
  const float* xrow = emb + (size_t)tok_s[b]*Ez;
  float a = 0.f;
  #pragma unroll
  for (int k = 0; k < Ez; k += 4) {
    float4 xv = *(const float4*)(xrow + k);
    float4 wv = *(const float4*)(wrow + k);
    a = fmaf(xv.x, wv.x, a); a = fmaf(xv.y, wv.y, a);
    a = fmaf(xv.z, wv.z, a); a = fmaf(xv.w, wv.w, a);
  }
  if (t > 0) {
    const float* hrow = h_in + b*Hz;
    #pragma unroll 8
    for (int k = 0; k < Hz; k += 4) {
      float4 xv = *(const float4*)(hrow + k);
      float4 wv = *(const float4*)(wrow + Ez + k);
      a = fmaf(xv.x, wv.x, a); a = fmaf(xv.y, wv.y, a);
      a = fmaf(xv.z, wv.z, a); a = fmaf(xv.w, wv.w, a);
    }
  }
  float bias = (q == 0) ? bi_[j] : (q == 1) ? bf_[j] : (q == 2) ? bog_[j] : bc_[j];
  a += bias;

  // ---- gather the 4 gate pre-activations across the 4-lane group ----
  int lane = tid & 63;
  int base = lane & ~3;
  float ai = __shfl(a, base + 0, 64);
  float af = __shfl(a, base + 1, 64);
  float ao = __shfl(a, base + 2, 64);
  float ac = __shfl(a, base + 3, 64);
  float gi = 1.f / (1.f + expf(-ai));
  float gf = 1.f / (1.f + expf(-af));
  float go = 1.f / (1.f + expf(-ao));
  float gc = tanhf(ac);
  float cold = (t > 0) ? c_g[b*Hz + j] : 0.f;
  float cn = gf*cold + gi*gc;
  float hn = go * tanhf(cn);
  if (q == 0)      h_out[b*Hz + j] = hn;
  else if (q == 1) c_g[b*Hz + j]   = cn;
  else if (q == 2) hT[j*Bz + b]    = hn;
}

// ---------------- logits: lane = batch row, 32 cols/lane in regs, w via scalar loads -----
__global__ __launch_bounds__(256) void k_logits(
    int t, const int* __restrict__ gnp,
    const float* __restrict__ hT,
    const float* __restrict__ Wo, const float* __restrict__ bo,
    u64* __restrict__ key_cur) {
  int gn = *gnp;
  if (t < gn) return;           // teacher step: no sampling needed
  int tid = threadIdx.x;
  int wv = tid >> 6, lane = tid & 63;
  int c0 = blockIdx.x * 128 + wv * 32;
  c0 = __builtin_amdgcn_readfirstlane(c0);

  float acc[32];
  #pragma unroll
  for (int jj = 0; jj < 32; ++jj) acc[jj] = bo[c0 + jj];   // uniform -> s_load

  #pragma unroll 2
  for (int k = 0; k < Hz; ++k) {
    float vh = hT[k*Bz + lane];                 // coalesced, per-lane row b=lane
    const float* wr = Wo + (size_t)k*Vz + c0;   // wave-uniform -> scalar loads
    #pragma unroll
    for (int jj = 0; jj < 32; ++jj) acc[jj] = fmaf(wr[jj], vh, acc[jj]);
  }

  // lane-local argmax over this lane's 32 columns (first-index-wins)
  float bv = acc[0]; int bc = c0;
  #pragma unroll
  for (int jj = 1; jj < 32; ++jj)
    if (acc[jj] > bv) { bv = acc[jj]; bc = c0 + jj; }

  u64 kv = ((u64)map_f32(bv) << 32) | (u32)(~(u32)bc);
  atomicMax(&key_cur[lane], kv);
}

// ---------------- final token (step T-1) -------------------------------------------------
__global__ void k_final(const int* __restrict__ gnp, const int* __restrict__ input_x,
                        const u64* __restrict__ key_last, int* __restrict__ out) {
  int b = threadIdx.x;
  int gn = *gnp;
  int tk;
  if (Tz - 1 < gn) tk = input_x[b*Tz + Tz - 1];
  else             tk = (int)(~(u32)(key_last[b] & 0xFFFFFFFFull));
  out[b*Tz + Tz - 1] = tk;
}

extern "C" void kernel_launch(void* const* d_in, const int* in_sizes, int n_in,
                              void* d_out, int out_size, void* d_ws, size_t ws_size,
                              hipStream_t stream) {
  const int*   input_x   = (const int*)d_in[0];
  const int*   gnp       = (const int*)d_in[1];
  const int*   start_tok = (const int*)d_in[2];
  const float* emb = (const float*)d_in[3];
  const float* Wi  = (const float*)d_in[4];
  const float* Ui  = (const float*)d_in[5];
  const float* bi  = (const float*)d_in[6];
  const float* Wf  = (const float*)d_in[7];
  const float* Uf  = (const float*)d_in[8];
  const float* bff = (const float*)d_in[9];
  const float* Wog = (const float*)d_in[10];
  const float* Uog = (const float*)d_in[11];
  const float* bog = (const float*)d_in[12];
  const float* Wc  = (const float*)d_in[13];
  const float* Uc  = (const float*)d_in[14];
  const float* bc  = (const float*)d_in[15];
  const float* Wo  = (const float*)d_in[16];
  const float* bo  = (const float*)d_in[17];
  int* out = (int*)d_out;

  float* wsf = (float*)d_ws;
  float* hA  = wsf;                      // 16384 f
  float* hB  = wsf + 16384;              // 16384 f
  float* c_g = wsf + 32768;              // 16384 f
  float* hT  = wsf + 49152;              // 16384 f
  u64*   key = (u64*)(wsf + 65536);      // 2*64 u64 = 256 f
  float* P2  = wsf + 65536 + 256;        // 327680 f

  k_prep<<<dim3(256), dim3(320), 0, stream>>>(Wi, Ui, Wf, Uf, Wog, Uog, Wc, Uc, P2, key);

  for (int t = 0; t < Tz; ++t) {
    const float* h_in = (t & 1) ? hA : hB;   // = buf[(t+1)&1]
    float*       h_out = (t & 1) ? hB : hA;  // = buf[t&1]
    const u64* key_prev = key + ((t + 1) & 1) * Bz;
    u64*       key_cur  = key + (t & 1) * Bz;
    k_gates<<<dim3(256), dim3(256), 0, stream>>>(
        t, gnp, input_x, start_tok, emb, P2, bi, bff, bog, bc,
        h_in, h_out, c_g, hT, key_prev, key_cur, out);
    k_logits<<<dim3(250), dim3(256), 0, stream>>>(
        t, gnp, hT, Wo, bo, key_cur);
  }
  k_final<<<dim3(1), dim3(64), 0, stream>>>(
      gnp, input_x, key + ((Tz - 1) & 1) * Bz, out);
}